// Round 5
// baseline (179.428 us; speedup 1.0000x reference)
//
#include <hip/hip_runtime.h>
#include <stdint.h>

#define NBATCH 2
#define LL 4096
#define CC 256
#define NEG_INF -3.0e38f

typedef short bf16x8 __attribute__((ext_vector_type(8)));
typedef float f32x4 __attribute__((ext_vector_type(4)));

__device__ __forceinline__ uint16_t f2bf(float f){
  union { float f; uint32_t u; } v; v.f = f;
  return (uint16_t)((v.u + 0x7fffu + ((v.u >> 16) & 1u)) >> 16);
}

// ---------------- cast fp32 -> bf16 ----------------
__global__ __launch_bounds__(256) void cast_bf16(
    const float* __restrict__ a, const float* __restrict__ b,
    uint16_t* __restrict__ oa, uint16_t* __restrict__ ob){
  int idx = blockIdx.x * 256 + threadIdx.x;   // float4 groups, grid exact
  float4 va = ((const float4*)a)[idx];
  float4 vb = ((const float4*)b)[idx];
  ushort4 ua, ub;
  ua.x = f2bf(va.x); ua.y = f2bf(va.y); ua.z = f2bf(va.z); ua.w = f2bf(va.w);
  ub.x = f2bf(vb.x); ub.y = f2bf(vb.y); ub.z = f2bf(vb.z); ub.w = f2bf(vb.w);
  ((ushort4*)oa)[idx] = ua;
  ((ushort4*)ob)[idx] = ub;
}

// ---------------- single conf pass, NO tile LDS, no K-loop barriers ----------
// 128x128 tile per block; fragments loaded directly from global (L1/L2 hot).
// Computes raw dot acc; emits per-(lt,st) partials: row/col exp-sums and
// row/col raw-c argmax. (Raw-c argmax == conf' argmax up to near-ties; a flip
// can only matter through a mask hit, which has ~3000x threshold margin.)
// C/D layout [m89]: l = lq*64 + r*16 + quad*4 + rr, s = sq*64 + j*16 + lr
__global__ __launch_bounds__(256) void conf_pass(
    const uint16_t* __restrict__ f0b, const uint16_t* __restrict__ f1b,
    float* __restrict__ rowSum, float* __restrict__ colSum,
    float2* __restrict__ rowPart, float2* __restrict__ colPart){
  __shared__ float rowS[128], colS[128];
  __shared__ float2 rb[128][2], cb[128][2];
  int st = blockIdx.x, lt = blockIdx.y, n = blockIdx.z;
  int t = threadIdx.x;
  if (t < 128){ rowS[t] = 0.f; colS[t] = 0.f; }
  const int wv = t >> 6, lane = t & 63, lr = lane & 15, quad = lane >> 4;
  const int lq = wv >> 1, sq = wv & 1;
  const uint16_t* A = f0b + (size_t)n*LL*CC;
  const uint16_t* B = f1b + (size_t)n*LL*CC;
  const uint16_t* arow[4];
  const uint16_t* brow[4];
  #pragma unroll
  for (int r = 0; r < 4; r++)
    arow[r] = A + (size_t)(lt*128 + lq*64 + r*16 + lr)*CC + quad*8;
  #pragma unroll
  for (int j = 0; j < 4; j++)
    brow[j] = B + (size_t)(st*128 + sq*64 + j*16 + lr)*CC + quad*8;
  f32x4 acc[4][4];
  #pragma unroll
  for (int r = 0; r < 4; r++)
    #pragma unroll
    for (int j = 0; j < 4; j++) acc[r][j] = (f32x4){0.f,0.f,0.f,0.f};
  #pragma unroll
  for (int kc = 0; kc < 8; kc++){
    bf16x8 a[4], b[4];
    #pragma unroll
    for (int r = 0; r < 4; r++) a[r] = *(const bf16x8*)(arow[r] + kc*32);
    #pragma unroll
    for (int j = 0; j < 4; j++) b[j] = *(const bf16x8*)(brow[j] + kc*32);
    #pragma unroll
    for (int r = 0; r < 4; r++)
      #pragma unroll
      for (int j = 0; j < 4; j++)
        acc[r][j] = __builtin_amdgcn_mfma_f32_16x16x32_bf16(a[r], b[j], acc[r][j], 0, 0, 0);
  }
  // ---- exp sums (c = acc/16) ----
  float rsum[4][4], csum[4] = {0.f,0.f,0.f,0.f};
  #pragma unroll
  for (int r = 0; r < 4; r++)
    #pragma unroll
    for (int rr = 0; rr < 4; rr++) rsum[r][rr] = 0.f;
  #pragma unroll
  for (int r = 0; r < 4; r++)
    #pragma unroll
    for (int j = 0; j < 4; j++)
      #pragma unroll
      for (int rr = 0; rr < 4; rr++){
        float e = expf(acc[r][j][rr] * 0.0625f);
        rsum[r][rr] += e;
        csum[j] += e;
      }
  #pragma unroll
  for (int msk = 1; msk <= 8; msk <<= 1)
    #pragma unroll
    for (int r = 0; r < 4; r++)
      #pragma unroll
      for (int rr = 0; rr < 4; rr++) rsum[r][rr] += __shfl_xor(rsum[r][rr], msk);
  #pragma unroll
  for (int msk = 16; msk <= 32; msk <<= 1)
    #pragma unroll
    for (int j = 0; j < 4; j++) csum[j] += __shfl_xor(csum[j], msk);
  if (lr == 0){
    #pragma unroll
    for (int r = 0; r < 4; r++)
      #pragma unroll
      for (int rr = 0; rr < 4; rr++)
        atomicAdd(&rowS[lq*64 + r*16 + quad*4 + rr], rsum[r][rr]);
  }
  if (quad == 0){
    #pragma unroll
    for (int j = 0; j < 4; j++) atomicAdd(&colS[sq*64 + j*16 + lr], csum[j]);
  }
  // ---- raw-c row argmax over this block's 128 s ----
  #pragma unroll
  for (int r = 0; r < 4; r++)
    #pragma unroll
    for (int rr = 0; rr < 4; rr++){
      float bk = NEG_INF; int bi = 0;
      #pragma unroll
      for (int j = 0; j < 4; j++){
        float v = acc[r][j][rr];
        if (v > bk){ bk = v; bi = st*128 + sq*64 + j*16 + lr; }
      }
      #pragma unroll
      for (int msk = 1; msk <= 8; msk <<= 1){
        float ok = __shfl_xor(bk, msk); int oi = __shfl_xor(bi, msk);
        if (ok > bk){ bk = ok; bi = oi; }
      }
      if (lr == 0) rb[lq*64 + r*16 + quad*4 + rr][sq] = make_float2(bk, __int_as_float(bi));
    }
  // ---- raw-c col argmax over this block's 128 l ----
  #pragma unroll
  for (int j = 0; j < 4; j++){
    float ck = NEG_INF; int ci = 0;
    #pragma unroll
    for (int r = 0; r < 4; r++)
      #pragma unroll
      for (int rr = 0; rr < 4; rr++){
        float v = acc[r][j][rr];
        if (v > ck){ ck = v; ci = lt*128 + lq*64 + r*16 + quad*4 + rr; }
      }
    #pragma unroll
    for (int msk = 16; msk <= 32; msk <<= 1){
      float ok = __shfl_xor(ck, msk); int oi = __shfl_xor(ci, msk);
      if (ok > ck){ ck = ok; ci = oi; }
    }
    if (quad == 0) cb[sq*64 + j*16 + lr][lq] = make_float2(ck, __int_as_float(ci));
  }
  __syncthreads();
  if (t < 128){
    rowSum[((size_t)n*LL + lt*128 + t)*32 + st] = rowS[t];
    colSum[((size_t)n*LL + st*128 + t)*32 + lt] = colS[t];
    float2 a = rb[t][0], b = rb[t][1];
    rowPart[((size_t)n*LL + lt*128 + t)*32 + st] = (a.x >= b.x) ? a : b;
    float2 c = cb[t][0], d = cb[t][1];
    colPart[((size_t)n*LL + st*128 + t)*32 + lt] = (c.x >= d.x) ? c : d;
  }
}

// ---------------- merged reduce: 32 partials -> R/Cv + argmax, both sides ---
__global__ __launch_bounds__(256) void reduce_all(
    const float* __restrict__ rowSum, const float* __restrict__ colSum,
    const float2* __restrict__ rowPart, const float2* __restrict__ colPart,
    float* __restrict__ R, float* __restrict__ Cv,
    float* __restrict__ rowKey, int* __restrict__ rowIdx,
    float* __restrict__ colKey, int* __restrict__ colIdx){
  int row = blockIdx.x * 4 + (threadIdx.x >> 6);
  int lane = threadIdx.x & 63;
  int side = blockIdx.y;
  const float*  sums = side ? colSum  : rowSum;
  const float2* part = side ? colPart : rowPart;
  float s = 0.f, v = NEG_INF; int i = 0;
  if (lane < 32){
    s = sums[(size_t)row*32 + lane];
    float2 p = part[(size_t)row*32 + lane];
    v = p.x; i = __float_as_int(p.y);
  }
  #pragma unroll
  for (int msk = 1; msk <= 32; msk <<= 1){
    s += __shfl_xor(s, msk);
    float v2 = __shfl_xor(v, msk); int i2 = __shfl_xor(i, msk);
    if (v2 > v){ v = v2; i = i2; }
  }
  if (lane == 0){
    if (side){ Cv[row] = s; colKey[row] = v; colIdx[row] = i; }
    else     { R [row] = s; rowKey[row] = v; rowIdx[row] = i; }
  }
}

// ---------------- on-the-fly fea for the rare mask hit ----------------
__device__ float fea_fly(const float* __restrict__ featn, int srow, int t){
  __shared__ float sred[9][4];
  __shared__ float ssem[9];
  int lane = t & 63, wv = t >> 6;
  int h = srow >> 6, xx = srow & 63;
  float fv = featn[(size_t)srow * CC + t];
  float uv[9];
  #pragma unroll
  for (int w = 0; w < 9; w++){
    int dy = w/3 - 1, dx = w%3 - 1;
    int y = h + dy, x = xx + dx;
    uv[w] = (y >= 0 && y < 64 && x >= 0 && x < 64) ? featn[(size_t)t * 4096 + y*64 + x] : 0.f;
  }
  __syncthreads();
  #pragma unroll
  for (int w = 0; w < 9; w++){
    float pvv = fv * uv[w];
    #pragma unroll
    for (int msk = 1; msk <= 32; msk <<= 1) pvv += __shfl_xor(pvv, msk);
    if (lane == 0) sred[w][wv] = pvv;
  }
  __syncthreads();
  if (t < 9) ssem[t] = (sred[t][0] + sred[t][1] + sred[t][2] + sred[t][3]) * (1.f/256.f);
  __syncthreads();
  float acc = 0.f;
  #pragma unroll
  for (int w = 0; w < 9; w++) acc += uv[w] * ssem[w];
  __syncthreads();
  return acc;
}

__device__ __forceinline__ float pool_window(const float* f, const float* s, int t){
  if (t < 160){
    int a = (t*8)/5, e = (t*8+12)/5;
    float sum = 0.f;
    for (int i = a; i < e; i++) sum += f[i];
    return sum / (float)(e - a);
  } else {
    int tt = t - 160;
    int a = (tt*8)/3, e = (tt*8+10)/3;
    float sum = 0.f;
    for (int i = a; i < e; i++) sum += s[i];
    return sum / (float)(e - a);
  }
}

// ---------------- fused tail: mutual-NN + dual pool + LN (2 barriers) -------
__global__ __launch_bounds__(256) void tail(
    const float* __restrict__ feat0, const float* __restrict__ feat1,
    const float* __restrict__ R, const float* __restrict__ Cv,
    const float* __restrict__ rowKey, const int* __restrict__ rowIdx,
    const float* __restrict__ colKey, const int* __restrict__ colIdx,
    const float* __restrict__ lnw, const float* __restrict__ lnb,
    float* __restrict__ out){
  int l = blockIdx.x, n = blockIdx.y, t = threadIdx.x;
  size_t base = (size_t)n * LL;
  float v0 = 0.f, v1 = 0.f;
  {
    int ss = rowIdx[base + l] & (LL - 1);   // clamp: robust under profiler replay
    // conf'(l,ss) = exp(2*c/16) / (R_l * C_ss)
    float val = expf(0.125f * rowKey[base + l]) / (R[base + l] * Cv[base + ss]);
    if (val > 0.2f && (colIdx[base + ss] & (LL - 1)) == l)
      v0 = fea_fly(feat1 + (size_t)n*LL*CC, ss, t) * (1.f/4096.f);
  }
  {
    int ss = colIdx[base + l] & (LL - 1);
    float val = expf(0.125f * colKey[base + l]) / (Cv[base + l] * R[base + ss]);
    if (val > 0.2f && (rowIdx[base + ss] & (LL - 1)) == l)
      v1 = fea_fly(feat0 + (size_t)n*LL*CC, ss, t) * (1.f/4096.f);
  }
  __shared__ float f0r[CC], f1r[CC], s0r[CC], s1r[CC];
  __shared__ float redA[2][4], redB[2][4];
  f0r[t] = feat0[(base + l)*CC + t];
  f1r[t] = feat1[(base + l)*CC + t];
  s0r[t] = v0;
  s1r[t] = v1;
  __syncthreads();
  float pA = pool_window(f0r, s0r, t);
  float pB = pool_window(f1r, s1r, t);
  float smA = pA, sqA = pA*pA, smB = pB, sqB = pB*pB;
  #pragma unroll
  for (int msk = 1; msk <= 32; msk <<= 1){
    smA += __shfl_xor(smA, msk);
    sqA += __shfl_xor(sqA, msk);
    smB += __shfl_xor(smB, msk);
    sqB += __shfl_xor(sqB, msk);
  }
  int lane = t & 63, wv = t >> 6;
  if (lane == 0){ redA[0][wv] = smA; redA[1][wv] = sqA; redB[0][wv] = smB; redB[1][wv] = sqB; }
  __syncthreads();
  float tsA = redA[0][0]+redA[0][1]+redA[0][2]+redA[0][3];
  float tqA = redA[1][0]+redA[1][1]+redA[1][2]+redA[1][3];
  float tsB = redB[0][0]+redB[0][1]+redB[0][2]+redB[0][3];
  float tqB = redB[1][0]+redB[1][1]+redB[1][2]+redB[1][3];
  float muA = tsA * (1.f/256.f), varA = tqA * (1.f/256.f) - muA*muA;
  float muB = tsB * (1.f/256.f), varB = tqB * (1.f/256.f) - muB*muB;
  float w = lnw[t], bsh = lnb[t];
  out[((size_t)n*LL + l)*CC + t]       = (pA - muA) * rsqrtf(varA + 1e-5f) * w + bsh;
  out[((size_t)(2 + n)*LL + l)*CC + t] = (pB - muB) * rsqrtf(varB + 1e-5f) * w + bsh;
}

extern "C" void kernel_launch(void* const* d_in, const int* in_sizes, int n_in,
                              void* d_out, int out_size, void* d_ws, size_t ws_size,
                              hipStream_t stream){
  const float* feat0 = (const float*)d_in[0];
  const float* feat1 = (const float*)d_in[1];
  const float* lnw   = (const float*)d_in[2];
  const float* lnb   = (const float*)d_in[3];
  float* out = (float*)d_out;
  char* ws = (char*)d_ws;
  const size_t MB = 1024 * 1024;
  uint16_t* f0b = (uint16_t*)(ws + 0);
  uint16_t* f1b = (uint16_t*)(ws + 4*MB);
  float* R  = (float*)(ws + 8*MB);                     // [8192]
  float* Cv = (float*)(ws + 8*MB + 32*1024);           // [8192]
  float* rowKey = (float*)(ws + 8*MB + 64*1024);       // [8192]
  int*   rowIdx = (int*)  (ws + 8*MB + 96*1024);
  float* colKey = (float*)(ws + 8*MB + 128*1024);
  int*   colIdx = (int*)  (ws + 8*MB + 160*1024);
  float2* rowPart = (float2*)(ws + 9*MB);              // [8192][32] = 2 MB
  float2* colPart = (float2*)(ws + 11*MB);             // 2 MB
  float*  rowSum  = (float*) (ws + 13*MB);             // [8192][32] = 1 MB
  float*  colSum  = (float*) (ws + 14*MB);             // 1 MB

  cast_bf16<<<2048, 256, 0, stream>>>(feat0, feat1, f0b, f1b);
  dim3 gconf(32, 32, NBATCH);
  conf_pass<<<gconf, 256, 0, stream>>>(f0b, f1b, rowSum, colSum, rowPart, colPart);
  dim3 gred(NBATCH*LL/4, 2);
  reduce_all<<<gred, 256, 0, stream>>>(rowSum, colSum, rowPart, colPart,
                                       R, Cv, rowKey, rowIdx, colKey, colIdx);
  dim3 gt(LL, NBATCH);
  tail<<<gt, 256, 0, stream>>>(feat0, feat1, R, Cv, rowKey, rowIdx,
                               colKey, colIdx, lnw, lnb, out);
}

// Round 6
// 139.305 us; speedup vs baseline: 1.2880x; 1.2880x over previous
//
#include <hip/hip_runtime.h>
#include <stdint.h>

#define NBATCH 2
#define LL 4096
#define CC 256
#define LSTR 68        // padded LDS row stride (bf16): b128 frag reads 2-way/free
#define KEXP 0.09016844f   // (1/16) * log2(e)  : exp(acc/16) = exp2(acc*KEXP)
#define KEXP2 0.18033688f  // (2/16) * log2(e)
#define IMIN (-2147483647 - 1)

typedef short bf16x8 __attribute__((ext_vector_type(8)));
typedef float f32x4 __attribute__((ext_vector_type(4)));

__device__ __forceinline__ uint16_t f2bf(float f){
  union { float f; uint32_t u; } v; v.f = f;
  return (uint16_t)((v.u + 0x7fffu + ((v.u >> 16) & 1u)) >> 16);
}

// ---------------- cast fp32 -> bf16 ----------------
__global__ __launch_bounds__(256) void cast_bf16(
    const float* __restrict__ a, const float* __restrict__ b,
    uint16_t* __restrict__ oa, uint16_t* __restrict__ ob){
  int idx = blockIdx.x * 256 + threadIdx.x;   // float4 groups, grid exact
  float4 va = ((const float4*)a)[idx];
  float4 vb = ((const float4*)b)[idx];
  ushort4 ua, ub;
  ua.x = f2bf(va.x); ua.y = f2bf(va.y); ua.z = f2bf(va.z); ua.w = f2bf(va.w);
  ub.x = f2bf(vb.x); ub.y = f2bf(vb.y); ub.z = f2bf(vb.z); ub.w = f2bf(vb.w);
  ((ushort4*)oa)[idx] = ua;
  ((ushort4*)ob)[idx] = ub;
}

// ---------------- single conf pass: 128x128 LDS-staged tile -----------------
// Emits per-(lt,st) partials: row/col exp-sums (f32) and row/col argmax as
// packed int keys: key = ((int)(acc*2048) << 12) | idx  (idx = 12-bit s or l).
// Monotone in acc; ties broken by idx (irrelevant: ~3000x threshold margin).
// C/D layout [m89]: l = lq*64 + r*16 + quad*4 + rr, s = sq*64 + j*16 + lr
__global__ __launch_bounds__(256) void conf_pass(
    const uint16_t* __restrict__ f0b, const uint16_t* __restrict__ f1b,
    float* __restrict__ rowSum, float* __restrict__ colSum,
    int* __restrict__ rowPart, int* __restrict__ colPart){
  __shared__ uint16_t Alds[128*LSTR], Blds[128*LSTR];
  __shared__ float rowS[2][128], colS[2][128];
  __shared__ int rb[128][2], cb[128][2];
  int st = blockIdx.x, lt = blockIdx.y, n = blockIdx.z;
  int t = threadIdx.x;
  const int wv = t >> 6, lane = t & 63, lr = lane & 15, quad = lane >> 4;
  const int lq = wv >> 1, sq = wv & 1;
  const uint16_t* A = f0b + (size_t)n*LL*CC;
  const uint16_t* B = f1b + (size_t)n*LL*CC;
  f32x4 acc[4][4];
  #pragma unroll
  for (int r = 0; r < 4; r++)
    #pragma unroll
    for (int j = 0; j < 4; j++) acc[r][j] = (f32x4){0.f,0.f,0.f,0.f};
  for (int kc = 0; kc < 4; kc++){
    __syncthreads();
    #pragma unroll
    for (int m = 0; m < 4; m++){
      int f = m*256 + t, row = f >> 3, kg = f & 7;
      *(float4*)(Alds + row*LSTR + kg*8) =
          *(const float4*)(A + (size_t)(lt*128 + row)*CC + kc*64 + kg*8);
      *(float4*)(Blds + row*LSTR + kg*8) =
          *(const float4*)(B + (size_t)(st*128 + row)*CC + kc*64 + kg*8);
    }
    __syncthreads();
    #pragma unroll
    for (int kk = 0; kk < 2; kk++){
      bf16x8 a[4], b[4];
      #pragma unroll
      for (int r = 0; r < 4; r++)
        a[r] = *(const bf16x8*)(Alds + (lq*64 + r*16 + lr)*LSTR + kk*32 + quad*8);
      #pragma unroll
      for (int j = 0; j < 4; j++)
        b[j] = *(const bf16x8*)(Blds + (sq*64 + j*16 + lr)*LSTR + kk*32 + quad*8);
      #pragma unroll
      for (int r = 0; r < 4; r++)
        #pragma unroll
        for (int j = 0; j < 4; j++)
          acc[r][j] = __builtin_amdgcn_mfma_f32_16x16x32_bf16(a[r], b[j], acc[r][j], 0, 0, 0);
    }
  }
  // ---- epilogue: exp-sums + packed argmax keys ----
  const int sbase = st*128 + sq*64 + lr;        // + j*16
  const int lbase = lt*128 + lq*64 + quad*4;    // + r*16 + rr
  float rsum[4][4], csum[4] = {0.f,0.f,0.f,0.f};
  int rkey[4][4], ckey[4] = {IMIN,IMIN,IMIN,IMIN};
  #pragma unroll
  for (int r = 0; r < 4; r++)
    #pragma unroll
    for (int rr = 0; rr < 4; rr++){ rsum[r][rr] = 0.f; rkey[r][rr] = IMIN; }
  #pragma unroll
  for (int r = 0; r < 4; r++)
    #pragma unroll
    for (int j = 0; j < 4; j++)
      #pragma unroll
      for (int rr = 0; rr < 4; rr++){
        float a = acc[r][j][rr];
        float e = exp2f(a * KEXP);
        rsum[r][rr] += e;
        csum[j] += e;
        int iqs = ((int)(a * 2048.f)) << 12;
        int sk = iqs + (sbase + j*16);
        int lk = iqs + (lbase + r*16 + rr);
        rkey[r][rr] = max(rkey[r][rr], sk);
        ckey[j] = max(ckey[j], lk);
      }
  #pragma unroll
  for (int msk = 1; msk <= 8; msk <<= 1)
    #pragma unroll
    for (int r = 0; r < 4; r++)
      #pragma unroll
      for (int rr = 0; rr < 4; rr++){
        rsum[r][rr] += __shfl_xor(rsum[r][rr], msk);
        rkey[r][rr] = max(rkey[r][rr], __shfl_xor(rkey[r][rr], msk));
      }
  #pragma unroll
  for (int msk = 16; msk <= 32; msk <<= 1)
    #pragma unroll
    for (int j = 0; j < 4; j++){
      csum[j] += __shfl_xor(csum[j], msk);
      ckey[j] = max(ckey[j], __shfl_xor(ckey[j], msk));
    }
  if (lr == 0){
    #pragma unroll
    for (int r = 0; r < 4; r++)
      #pragma unroll
      for (int rr = 0; rr < 4; rr++){
        int row = lq*64 + r*16 + quad*4 + rr;
        rowS[sq][row] = rsum[r][rr];   // single writer per slot
        rb[row][sq]   = rkey[r][rr];
      }
  }
  if (quad == 0){
    #pragma unroll
    for (int j = 0; j < 4; j++){
      int col = sq*64 + j*16 + lr;
      colS[lq][col] = csum[j];
      cb[col][lq]   = ckey[j];
    }
  }
  __syncthreads();
  if (t < 128){
    rowSum[((size_t)n*LL + lt*128 + t)*32 + st] = rowS[0][t] + rowS[1][t];
    colSum[((size_t)n*LL + st*128 + t)*32 + lt] = colS[0][t] + colS[1][t];
    rowPart[((size_t)n*LL + lt*128 + t)*32 + st] = max(rb[t][0], rb[t][1]);
    colPart[((size_t)n*LL + st*128 + t)*32 + lt] = max(cb[t][0], cb[t][1]);
  }
}

// ---------------- merged reduce: 32 partials -> R/Cv + packed argmax --------
__global__ __launch_bounds__(256) void reduce_all(
    const float* __restrict__ rowSum, const float* __restrict__ colSum,
    const int* __restrict__ rowPart, const int* __restrict__ colPart,
    float* __restrict__ R, float* __restrict__ Cv,
    int* __restrict__ rowKI, int* __restrict__ colKI){
  int row = blockIdx.x * 4 + (threadIdx.x >> 6);
  int lane = threadIdx.x & 63;
  int side = blockIdx.y;
  const float* sums = side ? colSum  : rowSum;
  const int*   part = side ? colPart : rowPart;
  float s = 0.f; int k = IMIN;
  if (lane < 32){
    s = sums[(size_t)row*32 + lane];
    k = part[(size_t)row*32 + lane];
  }
  #pragma unroll
  for (int msk = 1; msk <= 32; msk <<= 1){
    s += __shfl_xor(s, msk);
    k = max(k, __shfl_xor(k, msk));
  }
  if (lane == 0){
    if (side){ Cv[row] = s; colKI[row] = k; }
    else     { R [row] = s; rowKI[row] = k; }
  }
}

// ---------------- on-the-fly fea for the rare mask hit ----------------
__device__ float fea_fly(const float* __restrict__ featn, int srow, int t){
  __shared__ float sred[9][4];
  __shared__ float ssem[9];
  int lane = t & 63, wv = t >> 6;
  int h = srow >> 6, xx = srow & 63;
  float fv = featn[(size_t)srow * CC + t];
  float uv[9];
  #pragma unroll
  for (int w = 0; w < 9; w++){
    int dy = w/3 - 1, dx = w%3 - 1;
    int y = h + dy, x = xx + dx;
    uv[w] = (y >= 0 && y < 64 && x >= 0 && x < 64) ? featn[(size_t)t * 4096 + y*64 + x] : 0.f;
  }
  __syncthreads();
  #pragma unroll
  for (int w = 0; w < 9; w++){
    float pvv = fv * uv[w];
    #pragma unroll
    for (int msk = 1; msk <= 32; msk <<= 1) pvv += __shfl_xor(pvv, msk);
    if (lane == 0) sred[w][wv] = pvv;
  }
  __syncthreads();
  if (t < 9) ssem[t] = (sred[t][0] + sred[t][1] + sred[t][2] + sred[t][3]) * (1.f/256.f);
  __syncthreads();
  float acc = 0.f;
  #pragma unroll
  for (int w = 0; w < 9; w++) acc += uv[w] * ssem[w];
  __syncthreads();
  return acc;
}

__device__ __forceinline__ float pool_window(const float* f, const float* s, int t){
  if (t < 160){
    int a = (t*8)/5, e = (t*8+12)/5;
    float sum = 0.f;
    for (int i = a; i < e; i++) sum += f[i];
    return sum / (float)(e - a);
  } else {
    int tt = t - 160;
    int a = (tt*8)/3, e = (tt*8+10)/3;
    float sum = 0.f;
    for (int i = a; i < e; i++) sum += s[i];
    return sum / (float)(e - a);
  }
}

// ---------------- fused tail: mutual-NN + dual pool + LN --------------------
__global__ __launch_bounds__(256) void tail(
    const float* __restrict__ feat0, const float* __restrict__ feat1,
    const float* __restrict__ R, const float* __restrict__ Cv,
    const int* __restrict__ rowKI, const int* __restrict__ colKI,
    const float* __restrict__ lnw, const float* __restrict__ lnb,
    float* __restrict__ out){
  int l = blockIdx.x, n = blockIdx.y, t = threadIdx.x;
  size_t base = (size_t)n * LL;
  float v0 = 0.f, v1 = 0.f;
  {
    int kr = rowKI[base + l];
    int ss = kr & 4095;
    float araw = (float)(kr >> 12) * (1.f/2048.f);
    // conf'(l,ss) = exp(2*acc/16) / (R_l * C_ss)
    float val = exp2f(araw * KEXP2) / (R[base + l] * Cv[base + ss]);
    if (val > 0.2f && (colKI[base + ss] & 4095) == l)
      v0 = fea_fly(feat1 + (size_t)n*LL*CC, ss, t) * (1.f/4096.f);
  }
  {
    int kc = colKI[base + l];
    int ss = kc & 4095;
    float araw = (float)(kc >> 12) * (1.f/2048.f);
    float val = exp2f(araw * KEXP2) / (Cv[base + l] * R[base + ss]);
    if (val > 0.2f && (rowKI[base + ss] & 4095) == l)
      v1 = fea_fly(feat0 + (size_t)n*LL*CC, ss, t) * (1.f/4096.f);
  }
  __shared__ float f0r[CC], f1r[CC], s0r[CC], s1r[CC];
  __shared__ float redA[2][4], redB[2][4];
  f0r[t] = feat0[(base + l)*CC + t];
  f1r[t] = feat1[(base + l)*CC + t];
  s0r[t] = v0;
  s1r[t] = v1;
  __syncthreads();
  float pA = pool_window(f0r, s0r, t);
  float pB = pool_window(f1r, s1r, t);
  float smA = pA, sqA = pA*pA, smB = pB, sqB = pB*pB;
  #pragma unroll
  for (int msk = 1; msk <= 32; msk <<= 1){
    smA += __shfl_xor(smA, msk);
    sqA += __shfl_xor(sqA, msk);
    smB += __shfl_xor(smB, msk);
    sqB += __shfl_xor(sqB, msk);
  }
  int lane = t & 63, wv = t >> 6;
  if (lane == 0){ redA[0][wv] = smA; redA[1][wv] = sqA; redB[0][wv] = smB; redB[1][wv] = sqB; }
  __syncthreads();
  float tsA = redA[0][0]+redA[0][1]+redA[0][2]+redA[0][3];
  float tqA = redA[1][0]+redA[1][1]+redA[1][2]+redA[1][3];
  float tsB = redB[0][0]+redB[0][1]+redB[0][2]+redB[0][3];
  float tqB = redB[1][0]+redB[1][1]+redB[1][2]+redB[1][3];
  float muA = tsA * (1.f/256.f), varA = tqA * (1.f/256.f) - muA*muA;
  float muB = tsB * (1.f/256.f), varB = tqB * (1.f/256.f) - muB*muB;
  float w = lnw[t], bsh = lnb[t];
  out[((size_t)n*LL + l)*CC + t]       = (pA - muA) * rsqrtf(varA + 1e-5f) * w + bsh;
  out[((size_t)(2 + n)*LL + l)*CC + t] = (pB - muB) * rsqrtf(varB + 1e-5f) * w + bsh;
}

extern "C" void kernel_launch(void* const* d_in, const int* in_sizes, int n_in,
                              void* d_out, int out_size, void* d_ws, size_t ws_size,
                              hipStream_t stream){
  const float* feat0 = (const float*)d_in[0];
  const float* feat1 = (const float*)d_in[1];
  const float* lnw   = (const float*)d_in[2];
  const float* lnb   = (const float*)d_in[3];
  float* out = (float*)d_out;
  char* ws = (char*)d_ws;
  const size_t MB = 1024 * 1024;
  uint16_t* f0b = (uint16_t*)(ws + 0);
  uint16_t* f1b = (uint16_t*)(ws + 4*MB);
  float* R     = (float*)(ws + 8*MB);                  // [8192]
  float* Cv    = (float*)(ws + 8*MB + 32*1024);        // [8192]
  int*   rowKI = (int*)  (ws + 8*MB + 64*1024);        // [8192]
  int*   colKI = (int*)  (ws + 8*MB + 96*1024);        // [8192]
  float* rowSum = (float*)(ws + 9*MB);                 // [8192][32] = 1 MB
  float* colSum = (float*)(ws + 10*MB);                // 1 MB
  int*   rowPart = (int*) (ws + 11*MB);                // 1 MB
  int*   colPart = (int*) (ws + 12*MB);                // 1 MB

  cast_bf16<<<2048, 256, 0, stream>>>(feat0, feat1, f0b, f1b);
  dim3 gconf(32, 32, NBATCH);
  conf_pass<<<gconf, 256, 0, stream>>>(f0b, f1b, rowSum, colSum, rowPart, colPart);
  dim3 gred(NBATCH*LL/4, 2);
  reduce_all<<<gred, 256, 0, stream>>>(rowSum, colSum, rowPart, colPart,
                                       R, Cv, rowKI, colKI);
  dim3 gt(LL, NBATCH);
  tail<<<gt, 256, 0, stream>>>(feat0, feat1, R, Cv, rowKI, colKI, lnw, lnb, out);
}